// Round 2
// baseline (1793.576 us; speedup 1.0000x reference)
//
#include <hip/hip_runtime.h>

#define TN 2048

// ---------------- prep: repack weights into d_ws ----------------
// w1 [256][128] -> w1T [128][256]  (w1T[c][h] = w1[h][c])
// w2 [10][256]  -> w2Q [64][16][4] (w2Q[l][n][j] = w2[n][4l+j], n>=10 -> 0)
__global__ __launch_bounds__(256)
void prep_kernel(const float* __restrict__ w1, const float* __restrict__ w2,
                 float* __restrict__ w1T, float* __restrict__ w2Q) {
    int bid = blockIdx.x;
    if (bid < 32) {
        __shared__ float tile[32][33];
        int h0 = (bid >> 2) << 5;
        int c0 = (bid & 3) << 5;
        int tx = threadIdx.x & 31, ty = threadIdx.x >> 5;
        #pragma unroll
        for (int i = ty; i < 32; i += 8)
            tile[i][tx] = w1[(h0 + i) * 128 + (c0 + tx)];
        __syncthreads();
        #pragma unroll
        for (int i = ty; i < 32; i += 8)
            w1T[(c0 + i) * 256 + (h0 + tx)] = tile[tx][i];
    } else {
        for (int idx = threadIdx.x; idx < 64 * 16 * 4; idx += 256) {
            int l = idx >> 6, n = (idx >> 2) & 15, j = idx & 3;
            w2Q[idx] = (n < 10) ? w2[n * 256 + 4 * l + j] : 0.0f;
        }
    }
}

// branchless ascending-index extraction from a 128-bit (lo,hi) mask.
// returns `pad` when exhausted (points at a zeroed LDS row).
__device__ __forceinline__ int next_c(unsigned long long& lo, unsigned long long& hi, int pad) {
    bool have = (lo | hi) != 0ull;
    bool L = lo != 0ull;
    unsigned long long x = L ? lo : hi;
    unsigned long long xs = have ? x : 1ull;
    int c = __builtin_ctzll(xs) + (L ? 0 : 64);
    c = have ? c : pad;
    unsigned long long y = xs & (xs - 1ull);
    lo = L ? y : lo;
    hi = (!L && have) ? y : hi;
    return c;
}

__device__ __forceinline__ int next_l(unsigned long long& m, bool& have) {
    have = m != 0ull;
    unsigned long long xs = have ? m : 1ull;
    int l = __builtin_ctzll(xs);
    m = have ? (m & (m - 1ull)) : m;
    return l;   // 0 when !have (safe shift), predicated out by `have`
}

__device__ __forceinline__ float4 add4(float4 a, float4 b) {
    return make_float4(a.x + b.x, a.y + b.y, a.z + b.z, a.w + b.w);
}

// ---------------- main: one wave per batch ----------------
__global__ __launch_bounds__(256, 1)
void snn_main(const float* __restrict__ x,
              const float* __restrict__ convw,
              const float* __restrict__ w1T,
              const float* __restrict__ w2Q,
              float* __restrict__ out) {
    extern __shared__ float lds[];
    float* w1L  = lds;               // [129][256] floats (row 128 = zeros) : 132096 B
    float* w2QL = lds + 33024;       // [64][16][4] floats                  :  16384 B
    float* xL   = lds + 37120;       // [2064] floats (i <-> x[i-3], 0-pad) :   8256 B

    const int b = blockIdx.x;
    const int tid = threadIdx.x;

    {
        const float4* s4 = (const float4*)w1T;
        float4* d4 = (float4*)w1L;
        for (int i = tid; i < 8192; i += 256) d4[i] = s4[i];
        if (tid < 64) d4[8192 + tid] = make_float4(0.f, 0.f, 0.f, 0.f);  // zero row c=128
        const float4* s2 = (const float4*)w2Q;
        float4* d2 = (float4*)w2QL;
        for (int i = tid; i < 1024; i += 256) d2[i] = s2[i];
    }
    for (int i = tid; i < 2064; i += 256) {
        int l = i - 3;
        xL[i] = (l >= 0 && l < TN) ? x[b * TN + l] : 0.0f;
    }
    __syncthreads();
    if (tid >= 64) return;           // scan on wave 0 only

    const int lane = tid;
    const float4* w1q4 = ((const float4*)w1L) + lane;          // [c<<6] -> w1[c][4lane..4lane+3]
    const float4* w2q4 = ((const float4*)w2QL) + (lane & 15);  // [l<<4] -> w2[n][4l..4l+3]

    float cwa[7], cwb[7];
    #pragma unroll
    for (int k = 0; k < 7; ++k) {
        cwa[k] = convw[lane * 7 + k];
        cwb[k] = convw[(lane + 64) * 7 + k];
    }

    float v1a = 0.f, v1b = 0.f;                        // c = lane, lane+64
    float v20 = 0.f, v21 = 0.f, v22 = 0.f, v23 = 0.f;  // h = 4*lane + j
    float v3 = 0.f, acc = 0.f;                         // n = lane&15

    float xw[12];
    {
        float4 f0 = *(const float4*)(xL + 0);
        float4 f1 = *(const float4*)(xL + 4);
        float4 f2 = *(const float4*)(xL + 8);
        *(float4*)&xw[0] = f0; *(float4*)&xw[4] = f1; *(float4*)&xw[8] = f2;
    }

    // prologue: L1 for t=0
    unsigned long long ma, mb;
    {
        float xca = 0.f, xcb = 0.f;
        #pragma unroll
        for (int k = 0; k < 7; ++k) {
            float xv = xw[k];
            xca = fmaf(xv, cwa[k], xca);
            xcb = fmaf(xv, cwb[k], xcb);
        }
        float na = v1a + xca, nb = v1b + xcb;
        bool sa = na >= 1.0f, sb = nb >= 1.0f;
        ma = __ballot(sa); mb = __ballot(sb);
        v1a = sa ? 0.f : na; v1b = sb ? 0.f : nb;
    }

    for (int tb = 0; tb < TN; tb += 4) {
        float4 fn = *(const float4*)(xL + tb + 12);   // next-quad prefetch (hidden)

        #pragma unroll
        for (int p = 0; p < 4; ++p) {
            // ---- A: layer-2 gather issue for step t (8 slots, branch-free) ----
            unsigned long long lo = ma, hi = mb;
            int c0 = next_c(lo, hi, 128); float4 a0 = w1q4[c0 << 6];
            int c1 = next_c(lo, hi, 128); float4 a1 = w1q4[c1 << 6];
            int c2 = next_c(lo, hi, 128); float4 a2 = w1q4[c2 << 6];
            int c3 = next_c(lo, hi, 128); float4 a3 = w1q4[c3 << 6];
            int c4 = next_c(lo, hi, 128); float4 a4 = w1q4[c4 << 6];
            int c5 = next_c(lo, hi, 128); float4 a5 = w1q4[c5 << 6];
            int c6 = next_c(lo, hi, 128); float4 a6 = w1q4[c6 << 6];
            int c7 = next_c(lo, hi, 128); float4 a7 = w1q4[c7 << 6];

            // ---- B: layer-1 for step t+1 (independent VALU fills the LDS wait) ----
            float xca = 0.f, xcb = 0.f;
            #pragma unroll
            for (int k = 0; k < 7; ++k) {
                float xv = xw[p + 1 + k];
                xca = fmaf(xv, cwa[k], xca);
                xcb = fmaf(xv, cwb[k], xcb);
            }
            float na = v1a + xca, nb = v1b + xcb;
            bool sa = na >= 1.0f, sb = nb >= 1.0f;
            unsigned long long nma = __ballot(sa), nmb = __ballot(sb);
            v1a = sa ? 0.f : na; v1b = sb ? 0.f : nb;

            // ---- C: accumulate (ascending c; pads add exact +0), IF layer 2 ----
            float4 inc = a0;
            inc = add4(inc, a1); inc = add4(inc, a2); inc = add4(inc, a3);
            inc = add4(inc, a4); inc = add4(inc, a5); inc = add4(inc, a6);
            inc = add4(inc, a7);
            while (lo | hi) {      // rare: >8 spikes
                int c = next_c(lo, hi, 128);
                inc = add4(inc, w1q4[c << 6]);
            }
            float n0 = v20 + inc.x, n1 = v21 + inc.y, n2 = v22 + inc.z, n3 = v23 + inc.w;
            bool s0 = n0 >= 1.0f, s1 = n1 >= 1.0f, s2 = n2 >= 1.0f, s3 = n3 >= 1.0f;
            unsigned long long h0 = __ballot(s0), h1 = __ballot(s1);
            unsigned long long h2 = __ballot(s2), h3 = __ballot(s3);
            v20 = s0 ? 0.f : n0; v21 = s1 ? 0.f : n1;
            v22 = s2 ? 0.f : n2; v23 = s3 ? 0.f : n3;

            // ---- D: layer 3 (4 slots, predicated; ascending h) ----
            unsigned long long any = h0 | h1 | h2 | h3;
            if (any) {
                bool f0, f1, f2, f3;
                int l0 = next_l(any, f0); float4 q0 = w2q4[l0 << 4];
                int l1 = next_l(any, f1); float4 q1 = w2q4[l1 << 4];
                int l2 = next_l(any, f2); float4 q2 = w2q4[l2 << 4];
                int l3 = next_l(any, f3); float4 q3 = w2q4[l3 << 4];
                float inc3 = 0.f;
                inc3 += (f0 && ((h0 >> l0) & 1)) ? q0.x : 0.0f;
                inc3 += (f0 && ((h1 >> l0) & 1)) ? q0.y : 0.0f;
                inc3 += (f0 && ((h2 >> l0) & 1)) ? q0.z : 0.0f;
                inc3 += (f0 && ((h3 >> l0) & 1)) ? q0.w : 0.0f;
                inc3 += (f1 && ((h0 >> l1) & 1)) ? q1.x : 0.0f;
                inc3 += (f1 && ((h1 >> l1) & 1)) ? q1.y : 0.0f;
                inc3 += (f1 && ((h2 >> l1) & 1)) ? q1.z : 0.0f;
                inc3 += (f1 && ((h3 >> l1) & 1)) ? q1.w : 0.0f;
                inc3 += (f2 && ((h0 >> l2) & 1)) ? q2.x : 0.0f;
                inc3 += (f2 && ((h1 >> l2) & 1)) ? q2.y : 0.0f;
                inc3 += (f2 && ((h2 >> l2) & 1)) ? q2.z : 0.0f;
                inc3 += (f2 && ((h3 >> l2) & 1)) ? q2.w : 0.0f;
                inc3 += (f3 && ((h0 >> l3) & 1)) ? q3.x : 0.0f;
                inc3 += (f3 && ((h1 >> l3) & 1)) ? q3.y : 0.0f;
                inc3 += (f3 && ((h2 >> l3) & 1)) ? q3.z : 0.0f;
                inc3 += (f3 && ((h3 >> l3) & 1)) ? q3.w : 0.0f;
                while (any) {      // rare: >4 active l-groups
                    bool ft; int lt = next_l(any, ft);
                    float4 qt = w2q4[lt << 4];
                    inc3 += ((h0 >> lt) & 1) ? qt.x : 0.0f;
                    inc3 += ((h1 >> lt) & 1) ? qt.y : 0.0f;
                    inc3 += ((h2 >> lt) & 1) ? qt.z : 0.0f;
                    inc3 += ((h3 >> lt) & 1) ? qt.w : 0.0f;
                }
                float nn = v3 + inc3;
                bool ss = nn >= 1.0f;
                v3 = ss ? 0.f : nn;
                acc += ss ? 1.0f : 0.0f;
            }

            ma = nma; mb = nmb;
        }
        #pragma unroll
        for (int i = 0; i < 8; ++i) xw[i] = xw[i + 4];
        *(float4*)&xw[8] = fn;
    }

    if (lane < 10) out[b * 10 + lane] = acc * (1.0f / 2048.0f);
}

extern "C" void kernel_launch(void* const* d_in, const int* in_sizes, int n_in,
                              void* d_out, int out_size, void* d_ws, size_t ws_size,
                              hipStream_t stream) {
    const float* x     = (const float*)d_in[0];
    const float* convw = (const float*)d_in[1];
    const float* w1    = (const float*)d_in[2];
    const float* w2    = (const float*)d_in[3];
    float* w1T = (float*)d_ws;                 // 131072 B
    float* w2Q = (float*)d_ws + 32768;         //  16384 B

    prep_kernel<<<33, 256, 0, stream>>>(w1, w2, w1T, w2Q);

    const size_t ldsz = (33024 + 4096 + 2064) * sizeof(float);   // 156736 B
    (void)hipFuncSetAttribute(reinterpret_cast<const void*>(snn_main),
                              hipFuncAttributeMaxDynamicSharedMemorySize, (int)ldsz);
    snn_main<<<128, 256, ldsz, stream>>>(x, convw, w1T, w2Q, (float*)d_out);
}